// Round 12
// baseline (340.414 us; speedup 1.0000x reference)
//
#include <hip/hip_runtime.h>

// Problem constants (match reference)
constexpr int S_ = 200000;   // master nodes
constexpr int N_ = 250000;   // new nodes
// L = B = 64

constexpr int NCHUNK = (N_ + 63) / 64;        // 3907
constexpr int FUSE_BLOCKS = (NCHUNK + 1) / 2; // 1954, 2 chunks per block
constexpr int DEC_BLOCKS = (N_ + 31) / 32;    // 7813

constexpr int EMASK = 0x3FFFF;                // low 18 bits: master index

typedef __attribute__((ext_vector_type(8))) short bf16x8;
typedef __attribute__((ext_vector_type(4))) float f32x4;
typedef __attribute__((ext_vector_type(8))) unsigned short us8;

// ---------------------------------------------------------------------------
// K1: added[n] = (nn_m[nn_n[n]] != n); c_m histogram (added only, over nn_n);
//     ecnt[j] = #masters with nn_m=j  +  added[j]  (extended segment size).
__global__ void k_added_counts(const int* __restrict__ nn_n, const int* __restrict__ nn_m,
                               int* __restrict__ added, int* __restrict__ c_m,
                               int* __restrict__ ecnt) {
    int i = blockIdx.x * 256 + threadIdx.x;
    if (i < N_) {
        int m = nn_n[i];
        int a = (nn_m[m] != i) ? 1 : 0;
        added[i] = a;
        if (a) {
            atomicAdd(&c_m[m], 1);
            atomicAdd(&ecnt[i], 1);
        }
    }
    if (i < S_) {
        atomicAdd(&ecnt[nn_m[i]], 1);
    }
}

// ---------------------------------------------------------------------------
// K2: per-block sums of ecnt (1024 elements / block) for the exclusive scan.
__global__ void k_scan_blocksum(const int* __restrict__ ecnt, int* __restrict__ bsum) {
    __shared__ int sd[256];
    int b = blockIdx.x, t = threadIdx.x;
    int base = b * 1024 + t * 4;
    int s = 0;
#pragma unroll
    for (int k = 0; k < 4; k++) { int idx = base + k; if (idx < N_) s += ecnt[idx]; }
    sd[t] = s;
    __syncthreads();
    for (int off = 128; off > 0; off >>= 1) {
        if (t < off) sd[t] += sd[t + off];
        __syncthreads();
    }
    if (t == 0) bsum[b] = sd[0];
}

// K3: exclusive scan -> offs.
__global__ void k_scan_apply(const int* __restrict__ ecnt, const int* __restrict__ bsum,
                             int* __restrict__ offs) {
    __shared__ int sd[256];
    __shared__ int sp[256];
    int b = blockIdx.x, t = threadIdx.x;
    sp[t] = (t < b) ? bsum[t] : 0;
    __syncthreads();
    for (int off = 128; off > 0; off >>= 1) {
        if (t < off) sp[t] += sp[t + off];
        __syncthreads();
    }
    int prev = sp[0];

    int base = b * 1024 + t * 4;
    int v[4]; int s = 0;
#pragma unroll
    for (int k = 0; k < 4; k++) { int idx = base + k; v[k] = (idx < N_) ? ecnt[idx] : 0; s += v[k]; }
    sd[t] = s;
    __syncthreads();
    for (int off = 1; off < 256; off <<= 1) {
        int xv = (t >= off) ? sd[t - off] : 0;
        __syncthreads();
        sd[t] += xv;
        __syncthreads();
    }
    int run = prev + sd[t] - s;
#pragma unroll
    for (int k = 0; k < 4; k++) {
        int idx = base + k;
        if (idx < N_) offs[idx] = run;
        run += v[k];
    }
}

// K4: extended CSR fill — masters (nn_m inverse) plus the added contributor
//     nn_n[j] appended to segment j. Entries PACKED: m | (c_m[m] << 18)
//     (m < 2^18; c_m max ~15) so gather loops need no dependent c_m load.
__global__ void k_fill(const int* __restrict__ nn_m, const int* __restrict__ nn_n,
                       const int* __restrict__ added, const int* __restrict__ offs,
                       const int* __restrict__ c_m,
                       int* __restrict__ fill, int* __restrict__ elist) {
    int i = blockIdx.x * 256 + threadIdx.x;
    if (i < S_) {
        int j = nn_m[i];
        int p = atomicAdd(&fill[j], 1);
        elist[offs[j] + p] = i | (c_m[i] << 18);        // coalesced c_m read
    }
    if (i < N_ && added[i]) {
        int m = nn_n[i];
        int p = atomicAdd(&fill[i], 1);
        elist[offs[i] + p] = m | (c_m[m] << 18);        // random, L2-resident
    }
}

// ---------------------------------------------------------------------------
// K5 (FUSED k_wen + k_encode): per chunk of 64 j's,
//   phase G: We_n[j,:] = sum_{m in elist(j)} We_m[m,:] * rcp(c_m+1).
//     16 segments per wave; branch-free clamp, packed elist, rotate-prefetch.
//     Row gathers issued via inline-asm global_load_dword + single
//     s_waitcnt vmcnt(0) + sched_barrier(0) per round (v10-proven: VGPR
//     28->44 showed the 16 loads coexist; 78.8 us measured).
//     NOTE: the 2-deep counted-vmcnt pipeline (v12) RACED — compiler-emitted
//     entry loads share the vmcnt FIFO with our asm loads and the allocator
//     treats asm outputs as landed-at-issue. Counted waits here require the
//     whole phase in asm; not attempted headlessly again.
//     hi/lo bf16 split written to the 16 KB LDS fragment image
//     sw[sH*4096 + ct*1024 + hl*512 + (l15+16*kq2)*8 + i],
//     sH=wv>>1, kq2=(wv&1)*2+(u>>3), i=u&7  (each slot written once).
//   phase M: encode MFMA z[b,l] += x[b,n]*We_n[n,l], fp32 emulated by
//     bf16 hi/lo (ah*bh + al*bh + ah*bl); B via ds_read_b128 from sw.
// Epilogue: dense atomicAdd into zp2[row][b*64+l], row = blockIdx & 63.
__global__ __launch_bounds__(256) void k_wenc(
        const float* __restrict__ x, const float* __restrict__ We_m,
        const int* __restrict__ ecnt, const int* __restrict__ offs,
        const int* __restrict__ elist, float* __restrict__ zp2) {
    __shared__ unsigned short sw[8192];   // 16 KB fragment image (one chunk)
    int t = threadIdx.x;
    int lane = t & 63;
    int wv = __builtin_amdgcn_readfirstlane(t >> 6);
    int mrow = lane & 15;                 // A row within band / C col
    int kq = lane >> 4;                   // A k-quad / C row-quad
    int ct = lane >> 4, l15 = lane & 15;  // gather-epilogue coords
    const float* xbase = x + (size_t)(wv * 16 + mrow) * N_ + kq * 8;
    f32x4 acc[4];
#pragma unroll
    for (int i = 0; i < 4; i++) acc[i] = (f32x4){0.f, 0.f, 0.f, 0.f};

    for (int cc = 0; cc < 2; cc++) {
        int chk = blockIdx.x * 2 + cc;
        if (chk >= NCHUNK) break;         // block-uniform
        int n0 = chk * 64;

        __syncthreads();                  // prior MFMA phase done reading sw

        // ---------------- phase G: 16 segments per wave ----------------
        int jb = n0 + wv * 16;
        int c[16], o[16];
        float ag[16];
#pragma unroll
        for (int u = 0; u < 16; u++) {
            int j = jb + u;
            bool v = (j < N_);
            c[u] = v ? __builtin_amdgcn_readfirstlane(ecnt[j]) : 0;
            o[u] = v ? __builtin_amdgcn_readfirstlane(offs[j]) : 0;
            ag[u] = 0.f;
        }
        int cmax = 0;
#pragma unroll
        for (int u = 0; u < 16; u++) cmax = max(cmax, c[u]);
        if (cmax > 0) {
            int e[16];
#pragma unroll
            for (int u = 0; u < 16; u++)
                e[u] = __builtin_amdgcn_readfirstlane(elist[o[u]]);
            for (int q = 0; q < cmax; q++) {
                int en[16];
#pragma unroll
                for (int u = 0; u < 16; u++) {              // q+1 prefetch (lgkm)
                    int cl = max(c[u] - 1, 0);
                    int p = o[u] + min(q + 1, cl);
                    en[u] = __builtin_amdgcn_readfirstlane(elist[p]);
                }
                float row[16];
#pragma unroll
                for (int u = 0; u < 16; u++) {              // 16 forced gathers
                    int mmu = (q < c[u]) ? (e[u] & EMASK) : 0;
                    const float* ap = We_m + (size_t)mmu * 64 + lane;
                    asm volatile("global_load_dword %0, %1, off"
                                 : "=v"(row[u]) : "v"(ap));
                }
                asm volatile("s_waitcnt vmcnt(0)");
                __builtin_amdgcn_sched_barrier(0);          // rule #18 fence
#pragma unroll
                for (int u = 0; u < 16; u++) {
                    float r = __builtin_amdgcn_rcpf((float)((e[u] >> 18) + 1));
                    float sc = (q < c[u]) ? r : 0.0f;
                    ag[u] += row[u] * sc;
                }
#pragma unroll
                for (int u = 0; u < 16; u++) e[u] = en[u];
            }
        }
        // group epilogue: hi/lo split -> two contiguous us8 runs each
        us8 h0, l0, h1, l1;
#pragma unroll
        for (int s = 0; s < 8; s++) {
            float v0 = ag[s];
            unsigned u0 = __float_as_uint(v0);
            h0[s] = (unsigned short)(u0 >> 16);
            float r0 = v0 - __uint_as_float(u0 & 0xffff0000u);
            l0[s] = (unsigned short)(__float_as_uint(r0) >> 16);
            float v1 = ag[8 + s];
            unsigned u1 = __float_as_uint(v1);
            h1[s] = (unsigned short)(u1 >> 16);
            float r1 = v1 - __uint_as_float(u1 & 0xffff0000u);
            l1[s] = (unsigned short)(__float_as_uint(r1) >> 16);
        }
        int kq2a = (wv & 1) * 2;
        int sH = wv >> 1;
        int base0 = sH * 4096 + ct * 1024 + (l15 + 16 * kq2a) * 8;
        int base1 = base0 + 128;          // kq2a+1
        *(us8*)&sw[base0]       = h0;
        *(us8*)&sw[base0 + 512] = l0;
        *(us8*)&sw[base1]       = h1;
        *(us8*)&sw[base1 + 512] = l1;
        __syncthreads();                  // fragment image complete

        // ---------------- phase M: MFMA over the chunk ----------------
#pragma unroll
        for (int s = 0; s < 2; s++) {
            // A raw load (8 consecutive fp32 along k), tail-guarded
            float av[8];
            if (n0 + s * 32 + kq * 8 + 8 <= N_) {
                float4 a0 = *(const float4*)(xbase + n0 + s * 32);
                float4 a1 = *(const float4*)(xbase + n0 + s * 32 + 4);
                av[0] = a0.x; av[1] = a0.y; av[2] = a0.z; av[3] = a0.w;
                av[4] = a1.x; av[5] = a1.y; av[6] = a1.z; av[7] = a1.w;
            } else {
#pragma unroll
                for (int i = 0; i < 8; i++) av[i] = 0.f;
            }
            // B fragments from LDS (contiguous b128, conflict-free)
            bf16x8 bh[4], bl[4];
#pragma unroll
            for (int c2 = 0; c2 < 4; c2++) {
                bh[c2] = *(const bf16x8*)&sw[s * 4096 + c2 * 1024 + lane * 8];
                bl[c2] = *(const bf16x8*)&sw[s * 4096 + c2 * 1024 + 512 + lane * 8];
            }
            // split A into hi/lo bf16
            bf16x8 ah, al;
#pragma unroll
            for (int i = 0; i < 8; i++) {
                float v = av[i];
                unsigned u = __float_as_uint(v);
                ah[i] = (short)(u >> 16);
                float r = v - __uint_as_float(u & 0xffff0000u);
                al[i] = (short)(__float_as_uint(r) >> 16);
            }
            // 12 MFMAs: 4 col-tiles x 3 split terms
#pragma unroll
            for (int c2 = 0; c2 < 4; c2++) {
                acc[c2] = __builtin_amdgcn_mfma_f32_16x16x32_bf16(ah, bh[c2], acc[c2], 0, 0, 0);
                acc[c2] = __builtin_amdgcn_mfma_f32_16x16x32_bf16(al, bh[c2], acc[c2], 0, 0, 0);
                acc[c2] = __builtin_amdgcn_mfma_f32_16x16x32_bf16(ah, bl[c2], acc[c2], 0, 0, 0);
            }
        }
    }

    // Epilogue: C/D layout col=lane&15, row=(lane>>4)*4+reg (verified m89).
    int row = blockIdx.x & 63;
    float* zr = zp2 + row * 4096;
#pragma unroll
    for (int c2 = 0; c2 < 4; c2++) {
#pragma unroll
        for (int r = 0; r < 4; r++) {
            int b = wv * 16 + kq * 4 + r;
            int l = c2 * 16 + mrow;
            atomicAdd(&zr[b * 64 + l], acc[c2][r]);   // 16 consecutive floats/quad
        }
    }
}

// K7: z2g[l*64+b] = sum_rows zp2[b*64+l] + be[l].  (zp2 is b-major)
__global__ void k_zred(const float* __restrict__ zp2, const float* __restrict__ be_m,
                       float* __restrict__ z2g) {
    int slot = blockIdx.x * 256 + threadIdx.x;   // 16 blocks x 256, slot = b*64+l
    float s = 0.f;
    for (int r = 0; r < 64; r++) s += zp2[r * 4096 + slot];
    int b = slot >> 6, l = slot & 63;
    z2g[l * 64 + b] = s + be_m[l];
}

// ---------------------------------------------------------------------------
// K8: P[m,b] = sum_l z2g[l*64+b] * Wd_m[l,m] + bd_m[m].  P layout [S][64].
// acc[16] per thread (lane = m, wave bg owns b-group). Per-thread float4 row
// stores (v9-proven; all 4 stores of a lane hit the same 256-B row and L2
// write-combines — the v11 LDS staging was slower).
__global__ __launch_bounds__(256) void k_pmat(
        const float* __restrict__ Wd_m, const float* __restrict__ bd_m,
        const float* __restrict__ z2g, float* __restrict__ P) {
    __shared__ float ws[64 * 64];
    int t = threadIdx.x;
    int m0 = blockIdx.x * 64;
    // stage Wd_m[l][m0:m0+64] tile: 4 float4 loads per thread, coalesced
#pragma unroll
    for (int r = 0; r < 4; r++) {
        int flat = r * 256 + t;          // 0..1023
        int l = flat >> 4;               // 0..63
        int c4 = flat & 15;              // 0..15
        float4 v = *(const float4*)&Wd_m[(size_t)l * S_ + m0 + c4 * 4];
        *(float4*)&ws[l * 64 + c4 * 4] = v;
    }
    __syncthreads();

    int m = t & 63;
    int bg = __builtin_amdgcn_readfirstlane(t >> 6);   // wave-uniform b-group
    float bd = bd_m[m0 + m];
    float acc[16];
#pragma unroll
    for (int q = 0; q < 16; q++) acc[q] = bd;
    const float* zb = z2g + bg * 16;
#pragma unroll 4
    for (int l = 0; l < 64; l++) {
        float w = ws[l * 64 + m];
        const float* zr = zb + l * 64;   // wave-uniform -> s_load_dwordx16
#pragma unroll
        for (int q = 0; q < 16; q++) acc[q] += w * zr[q];
    }

    float4* Pv = (float4*)&P[(size_t)(m0 + m) * 64 + bg * 16];
#pragma unroll
    for (int q4 = 0; q4 < 4; q4++)
        Pv[q4] = make_float4(acc[q4 * 4 + 0], acc[q4 * 4 + 1],
                             acc[q4 * 4 + 2], acc[q4 * 4 + 3]);
}

// ---------------------------------------------------------------------------
// K9: out[b,j] = (sum_{m in elist(j)} P[m,b]) / max(ecnt[j],1).
// Branch-free 8-deep structure with rotate-prefetch of packed elist entries
// (round-8-proven; the asm-16 variant regressed here). lane = b; 32-j tile
// through LDS for coalesced out writes.
__global__ __launch_bounds__(256) void k_decode(const float* __restrict__ P,
        const int* __restrict__ ecnt, const int* __restrict__ offs,
        const int* __restrict__ elist, float* __restrict__ out) {
    __shared__ float tile[32][65];
    int t = threadIdx.x;
    int wv = __builtin_amdgcn_readfirstlane(t >> 6);
    int lane = t & 63;
    int j0 = blockIdx.x * 32;
    int jb = j0 + wv * 8;
    int c[8], o[8], cl[8];
    float acc[8];
#pragma unroll
    for (int s = 0; s < 8; s++) {
        int j = jb + s;
        bool v = (j < N_);
        c[s] = v ? __builtin_amdgcn_readfirstlane(ecnt[j]) : 0;
        o[s] = v ? __builtin_amdgcn_readfirstlane(offs[j]) : 0;
        cl[s] = max(c[s] - 1, 0);
        acc[s] = 0.f;
    }
    int cmax = 0;
#pragma unroll
    for (int s = 0; s < 8; s++) cmax = max(cmax, c[s]);

    if (cmax > 0) {
        int e[8];
#pragma unroll
        for (int s = 0; s < 8; s++)
            e[s] = __builtin_amdgcn_readfirstlane(elist[o[s]]);
        for (int q = 0; q < cmax; q++) {
            int en[8];
#pragma unroll
            for (int s = 0; s < 8; s++) {
                int p = o[s] + min(q + 1, cl[s]);
                en[s] = __builtin_amdgcn_readfirstlane(elist[p]);
            }
            int mm[8]; float sc[8];
#pragma unroll
            for (int s = 0; s < 8; s++) {
                bool valid = (q < c[s]);
                mm[s] = valid ? (e[s] & EMASK) : 0;
                sc[s] = valid ? 1.0f : 0.0f;
            }
            float row[8];
#pragma unroll
            for (int s = 0; s < 8; s++)
                row[s] = P[(size_t)mm[s] * 64 + lane];     // 8 gathers in flight
#pragma unroll
            for (int s = 0; s < 8; s++)
                acc[s] += row[s] * sc[s];
#pragma unroll
            for (int s = 0; s < 8; s++) e[s] = en[s];
        }
    }
#pragma unroll
    for (int s = 0; s < 8; s++) {
        int cc = (c[s] > 1) ? c[s] : 1;
        tile[wv * 8 + s][lane] = acc[s] * (1.0f / (float)cc);
    }
    __syncthreads();
#pragma unroll
    for (int r = 0; r < 8; r++) {
        int b = r * 8 + (t >> 5);
        int j = j0 + (t & 31);
        if (j < N_) out[(size_t)b * N_ + j] = tile[t & 31][b];
    }
}

// ---------------------------------------------------------------------------
extern "C" void kernel_launch(void* const* d_in, const int* in_sizes, int n_in,
                              void* d_out, int out_size, void* d_ws, size_t ws_size,
                              hipStream_t stream) {
    const float* We_m = (const float*)d_in[0];
    const float* be_m = (const float*)d_in[1];
    const float* Wd_m = (const float*)d_in[2];
    const float* bd_m = (const float*)d_in[3];
    const float* x    = (const float*)d_in[4];
    const int*   nn_n = (const int*)d_in[5];
    const int*   nn_m = (const int*)d_in[6];
    float* out = (float*)d_out;
    char* ws = (char*)d_ws;

    // Workspace layout (byte offsets). Region 0 holds P [S,64] (51.2 MB)
    // for the decode phase.
    float* P     = (float*)(ws + 0);
    int*   c_m   = (int*)(ws + 64012288);      //    800,000 B (zeroed)
    int*   ecnt  = (int*)(ws + 64812288);      //  1,000,000 B (zeroed)
    int*   fill  = (int*)(ws + 65812288);      //  1,000,000 B (zeroed)
    int*   added = (int*)(ws + 66812288);      //  1,000,000 B
    int*   offs  = (int*)(ws + 67812288);      //  1,000,000 B
    int*   elist = (int*)(ws + 68812288);      //  2,000,000 B (<= (S+N)*4 = 1.8 MB)
    float* zp2   = (float*)(ws + 70812288);    //  1,048,576 B (64 x 4096, zeroed)
    float* z2g   = (float*)(ws + 71860864);    //     16,384 B
    int*   bsum  = (int*)(ws + 71877248);      //      1,024 B
    // total ~71.9 MB

    hipMemsetAsync(ws + 64012288, 0, 2800000, stream);       // c_m, ecnt, fill
    hipMemsetAsync(zp2, 0, 1048576, stream);                 // zp2

    k_added_counts<<<977, 256, 0, stream>>>(nn_n, nn_m, added, c_m, ecnt);
    k_scan_blocksum<<<245, 256, 0, stream>>>(ecnt, bsum);
    k_scan_apply<<<245, 256, 0, stream>>>(ecnt, bsum, offs);
    k_fill<<<977, 256, 0, stream>>>(nn_m, nn_n, added, offs, c_m, fill, elist);
    k_wenc<<<FUSE_BLOCKS, 256, 0, stream>>>(x, We_m, ecnt, offs, elist, zp2);
    k_zred<<<16, 256, 0, stream>>>(zp2, be_m, z2g);
    k_pmat<<<3125, 256, 0, stream>>>(Wd_m, bd_m, z2g, P);
    k_decode<<<DEC_BLOCKS, 256, 0, stream>>>(P, ecnt, offs, elist, out);
}

// Round 13
// 336.802 us; speedup vs baseline: 1.0107x; 1.0107x over previous
//
#include <hip/hip_runtime.h>

// Problem constants (match reference)
constexpr int S_ = 200000;   // master nodes
constexpr int N_ = 250000;   // new nodes
// L = B = 64

constexpr int NCHUNK = (N_ + 63) / 64;        // 3907
constexpr int FUSE_BLOCKS = (NCHUNK + 1) / 2; // 1954, 2 chunks per block
constexpr int DEC_BLOCKS = (N_ + 31) / 32;    // 7813

constexpr int EMASK = 0x3FFFF;                // low 18 bits: master index

typedef __attribute__((ext_vector_type(8))) short bf16x8;
typedef __attribute__((ext_vector_type(4))) float f32x4;
typedef __attribute__((ext_vector_type(8))) unsigned short us8;

// ---------------------------------------------------------------------------
// K1: added[n] = (nn_m[nn_n[n]] != n); c_m histogram (added only, over nn_n);
//     ecnt[j] = #masters with nn_m=j  +  added[j]  (extended segment size).
__global__ void k_added_counts(const int* __restrict__ nn_n, const int* __restrict__ nn_m,
                               int* __restrict__ added, int* __restrict__ c_m,
                               int* __restrict__ ecnt) {
    int i = blockIdx.x * 256 + threadIdx.x;
    if (i < N_) {
        int m = nn_n[i];
        int a = (nn_m[m] != i) ? 1 : 0;
        added[i] = a;
        if (a) {
            atomicAdd(&c_m[m], 1);
            atomicAdd(&ecnt[i], 1);
        }
    }
    if (i < S_) {
        atomicAdd(&ecnt[nn_m[i]], 1);
    }
}

// ---------------------------------------------------------------------------
// K2: per-block sums of ecnt (1024 elements / block) for the exclusive scan.
__global__ void k_scan_blocksum(const int* __restrict__ ecnt, int* __restrict__ bsum) {
    __shared__ int sd[256];
    int b = blockIdx.x, t = threadIdx.x;
    int base = b * 1024 + t * 4;
    int s = 0;
#pragma unroll
    for (int k = 0; k < 4; k++) { int idx = base + k; if (idx < N_) s += ecnt[idx]; }
    sd[t] = s;
    __syncthreads();
    for (int off = 128; off > 0; off >>= 1) {
        if (t < off) sd[t] += sd[t + off];
        __syncthreads();
    }
    if (t == 0) bsum[b] = sd[0];
}

// K3: exclusive scan -> offs.
__global__ void k_scan_apply(const int* __restrict__ ecnt, const int* __restrict__ bsum,
                             int* __restrict__ offs) {
    __shared__ int sd[256];
    __shared__ int sp[256];
    int b = blockIdx.x, t = threadIdx.x;
    sp[t] = (t < b) ? bsum[t] : 0;
    __syncthreads();
    for (int off = 128; off > 0; off >>= 1) {
        if (t < off) sp[t] += sp[t + off];
        __syncthreads();
    }
    int prev = sp[0];

    int base = b * 1024 + t * 4;
    int v[4]; int s = 0;
#pragma unroll
    for (int k = 0; k < 4; k++) { int idx = base + k; v[k] = (idx < N_) ? ecnt[idx] : 0; s += v[k]; }
    sd[t] = s;
    __syncthreads();
    for (int off = 1; off < 256; off <<= 1) {
        int xv = (t >= off) ? sd[t - off] : 0;
        __syncthreads();
        sd[t] += xv;
        __syncthreads();
    }
    int run = prev + sd[t] - s;
#pragma unroll
    for (int k = 0; k < 4; k++) {
        int idx = base + k;
        if (idx < N_) offs[idx] = run;
        run += v[k];
    }
}

// K4: extended CSR fill — masters (nn_m inverse) plus the added contributor
//     nn_n[j] appended to segment j. Entries PACKED: m | (c_m[m] << 18)
//     (m < 2^18; c_m max ~15) so gather loops need no dependent c_m load.
__global__ void k_fill(const int* __restrict__ nn_m, const int* __restrict__ nn_n,
                       const int* __restrict__ added, const int* __restrict__ offs,
                       const int* __restrict__ c_m,
                       int* __restrict__ fill, int* __restrict__ elist) {
    int i = blockIdx.x * 256 + threadIdx.x;
    if (i < S_) {
        int j = nn_m[i];
        int p = atomicAdd(&fill[j], 1);
        elist[offs[j] + p] = i | (c_m[i] << 18);        // coalesced c_m read
    }
    if (i < N_ && added[i]) {
        int m = nn_n[i];
        int p = atomicAdd(&fill[i], 1);
        elist[offs[i] + p] = m | (c_m[m] << 18);        // random, L2-resident
    }
}

// ---------------------------------------------------------------------------
// K5 (FUSED k_wen + k_encode): per chunk of 64 j's,
//   phase G: We_n[j,:] = sum_{m in elist(j)} We_m[m,:] * rcp(c_m+1).
//     16 segments per wave; branch-free clamp, packed elist.
//     ROUND ORDER (v14 fix): issue the 16 asm row gathers FIRST, then the
//     16 next-round elist entry loads, then ONE s_waitcnt vmcnt(0) +
//     sched_barrier(0). v13 issued the entry loads first; their
//     readfirstlane consumption forced a compiler-inserted full drain
//     BEFORE the row gathers even issued -> TWO serial latency drains per
//     round. Reordering overlaps both load batches under one drain.
//     Same drain-to-zero discipline as the v10/v13-proven kernel (the v12
//     counted-vmcnt pipeline raced and is not retried).
//     hi/lo bf16 split written to the 16 KB LDS fragment image
//     sw[sH*4096 + ct*1024 + hl*512 + (l15+16*kq2)*8 + i],
//     sH=wv>>1, kq2=(wv&1)*2+(u>>3), i=u&7  (each slot written once).
//   phase M: encode MFMA z[b,l] += x[b,n]*We_n[n,l], fp32 emulated by
//     bf16 hi/lo (ah*bh + al*bh + ah*bl); B via ds_read_b128 from sw.
// Epilogue: dense atomicAdd into zp2[row][b*64+l], row = blockIdx & 63.
__global__ __launch_bounds__(256) void k_wenc(
        const float* __restrict__ x, const float* __restrict__ We_m,
        const int* __restrict__ ecnt, const int* __restrict__ offs,
        const int* __restrict__ elist, float* __restrict__ zp2) {
    __shared__ unsigned short sw[8192];   // 16 KB fragment image (one chunk)
    int t = threadIdx.x;
    int lane = t & 63;
    int wv = __builtin_amdgcn_readfirstlane(t >> 6);
    int mrow = lane & 15;                 // A row within band / C col
    int kq = lane >> 4;                   // A k-quad / C row-quad
    int ct = lane >> 4, l15 = lane & 15;  // gather-epilogue coords
    const float* xbase = x + (size_t)(wv * 16 + mrow) * N_ + kq * 8;
    f32x4 acc[4];
#pragma unroll
    for (int i = 0; i < 4; i++) acc[i] = (f32x4){0.f, 0.f, 0.f, 0.f};

    for (int cc = 0; cc < 2; cc++) {
        int chk = blockIdx.x * 2 + cc;
        if (chk >= NCHUNK) break;         // block-uniform
        int n0 = chk * 64;

        __syncthreads();                  // prior MFMA phase done reading sw

        // ---------------- phase G: 16 segments per wave ----------------
        int jb = n0 + wv * 16;
        int c[16], o[16];
        float ag[16];
#pragma unroll
        for (int u = 0; u < 16; u++) {
            int j = jb + u;
            bool v = (j < N_);
            c[u] = v ? __builtin_amdgcn_readfirstlane(ecnt[j]) : 0;
            o[u] = v ? __builtin_amdgcn_readfirstlane(offs[j]) : 0;
            ag[u] = 0.f;
        }
        int cmax = 0;
#pragma unroll
        for (int u = 0; u < 16; u++) cmax = max(cmax, c[u]);
        if (cmax > 0) {
            int e[16];
#pragma unroll
            for (int u = 0; u < 16; u++)
                e[u] = __builtin_amdgcn_readfirstlane(elist[o[u]]);
            for (int q = 0; q < cmax; q++) {
                float row[16];
#pragma unroll
                for (int u = 0; u < 16; u++) {              // gathers issue FIRST
                    int mmu = (q < c[u]) ? (e[u] & EMASK) : 0;
                    const float* ap = We_m + (size_t)mmu * 64 + lane;
                    asm volatile("global_load_dword %0, %1, off"
                                 : "=v"(row[u]) : "v"(ap));
                }
                int en[16];
#pragma unroll
                for (int u = 0; u < 16; u++) {              // entry loads overlap
                    int cl = max(c[u] - 1, 0);
                    int p = o[u] + min(q + 1, cl);
                    en[u] = __builtin_amdgcn_readfirstlane(elist[p]);
                }
                asm volatile("s_waitcnt vmcnt(0)");         // ONE drain per round
                __builtin_amdgcn_sched_barrier(0);          // rule #18 fence
#pragma unroll
                for (int u = 0; u < 16; u++) {
                    float r = __builtin_amdgcn_rcpf((float)((e[u] >> 18) + 1));
                    float sc = (q < c[u]) ? r : 0.0f;
                    ag[u] += row[u] * sc;
                }
#pragma unroll
                for (int u = 0; u < 16; u++) e[u] = en[u];
            }
        }
        // group epilogue: hi/lo split -> two contiguous us8 runs each
        us8 h0, l0, h1, l1;
#pragma unroll
        for (int s = 0; s < 8; s++) {
            float v0 = ag[s];
            unsigned u0 = __float_as_uint(v0);
            h0[s] = (unsigned short)(u0 >> 16);
            float r0 = v0 - __uint_as_float(u0 & 0xffff0000u);
            l0[s] = (unsigned short)(__float_as_uint(r0) >> 16);
            float v1 = ag[8 + s];
            unsigned u1 = __float_as_uint(v1);
            h1[s] = (unsigned short)(u1 >> 16);
            float r1 = v1 - __uint_as_float(u1 & 0xffff0000u);
            l1[s] = (unsigned short)(__float_as_uint(r1) >> 16);
        }
        int kq2a = (wv & 1) * 2;
        int sH = wv >> 1;
        int base0 = sH * 4096 + ct * 1024 + (l15 + 16 * kq2a) * 8;
        int base1 = base0 + 128;          // kq2a+1
        *(us8*)&sw[base0]       = h0;
        *(us8*)&sw[base0 + 512] = l0;
        *(us8*)&sw[base1]       = h1;
        *(us8*)&sw[base1 + 512] = l1;
        __syncthreads();                  // fragment image complete

        // ---------------- phase M: MFMA over the chunk ----------------
#pragma unroll
        for (int s = 0; s < 2; s++) {
            // A raw load (8 consecutive fp32 along k), tail-guarded
            float av[8];
            if (n0 + s * 32 + kq * 8 + 8 <= N_) {
                float4 a0 = *(const float4*)(xbase + n0 + s * 32);
                float4 a1 = *(const float4*)(xbase + n0 + s * 32 + 4);
                av[0] = a0.x; av[1] = a0.y; av[2] = a0.z; av[3] = a0.w;
                av[4] = a1.x; av[5] = a1.y; av[6] = a1.z; av[7] = a1.w;
            } else {
#pragma unroll
                for (int i = 0; i < 8; i++) av[i] = 0.f;
            }
            // B fragments from LDS (contiguous b128, conflict-free)
            bf16x8 bh[4], bl[4];
#pragma unroll
            for (int c2 = 0; c2 < 4; c2++) {
                bh[c2] = *(const bf16x8*)&sw[s * 4096 + c2 * 1024 + lane * 8];
                bl[c2] = *(const bf16x8*)&sw[s * 4096 + c2 * 1024 + 512 + lane * 8];
            }
            // split A into hi/lo bf16
            bf16x8 ah, al;
#pragma unroll
            for (int i = 0; i < 8; i++) {
                float v = av[i];
                unsigned u = __float_as_uint(v);
                ah[i] = (short)(u >> 16);
                float r = v - __uint_as_float(u & 0xffff0000u);
                al[i] = (short)(__float_as_uint(r) >> 16);
            }
            // 12 MFMAs: 4 col-tiles x 3 split terms
#pragma unroll
            for (int c2 = 0; c2 < 4; c2++) {
                acc[c2] = __builtin_amdgcn_mfma_f32_16x16x32_bf16(ah, bh[c2], acc[c2], 0, 0, 0);
                acc[c2] = __builtin_amdgcn_mfma_f32_16x16x32_bf16(al, bh[c2], acc[c2], 0, 0, 0);
                acc[c2] = __builtin_amdgcn_mfma_f32_16x16x32_bf16(ah, bl[c2], acc[c2], 0, 0, 0);
            }
        }
    }

    // Epilogue: C/D layout col=lane&15, row=(lane>>4)*4+reg (verified m89).
    int row = blockIdx.x & 63;
    float* zr = zp2 + row * 4096;
#pragma unroll
    for (int c2 = 0; c2 < 4; c2++) {
#pragma unroll
        for (int r = 0; r < 4; r++) {
            int b = wv * 16 + kq * 4 + r;
            int l = c2 * 16 + mrow;
            atomicAdd(&zr[b * 64 + l], acc[c2][r]);   // 16 consecutive floats/quad
        }
    }
}

// K7: z2g[l*64+b] = sum_rows zp2[b*64+l] + be[l].  (zp2 is b-major)
__global__ void k_zred(const float* __restrict__ zp2, const float* __restrict__ be_m,
                       float* __restrict__ z2g) {
    int slot = blockIdx.x * 256 + threadIdx.x;   // 16 blocks x 256, slot = b*64+l
    float s = 0.f;
    for (int r = 0; r < 64; r++) s += zp2[r * 4096 + slot];
    int b = slot >> 6, l = slot & 63;
    z2g[l * 64 + b] = s + be_m[l];
}

// ---------------------------------------------------------------------------
// K8: P[m,b] = sum_l z2g[l*64+b] * Wd_m[l,m] + bd_m[m].  P layout [S][64].
// acc[16] per thread (lane = m, wave bg owns b-group). Per-thread float4 row
// stores (v9-proven; all 4 stores of a lane hit the same 256-B row and L2
// write-combines — the v11 LDS staging was slower).
__global__ __launch_bounds__(256) void k_pmat(
        const float* __restrict__ Wd_m, const float* __restrict__ bd_m,
        const float* __restrict__ z2g, float* __restrict__ P) {
    __shared__ float ws[64 * 64];
    int t = threadIdx.x;
    int m0 = blockIdx.x * 64;
    // stage Wd_m[l][m0:m0+64] tile: 4 float4 loads per thread, coalesced
#pragma unroll
    for (int r = 0; r < 4; r++) {
        int flat = r * 256 + t;          // 0..1023
        int l = flat >> 4;               // 0..63
        int c4 = flat & 15;              // 0..15
        float4 v = *(const float4*)&Wd_m[(size_t)l * S_ + m0 + c4 * 4];
        *(float4*)&ws[l * 64 + c4 * 4] = v;
    }
    __syncthreads();

    int m = t & 63;
    int bg = __builtin_amdgcn_readfirstlane(t >> 6);   // wave-uniform b-group
    float bd = bd_m[m0 + m];
    float acc[16];
#pragma unroll
    for (int q = 0; q < 16; q++) acc[q] = bd;
    const float* zb = z2g + bg * 16;
#pragma unroll 4
    for (int l = 0; l < 64; l++) {
        float w = ws[l * 64 + m];
        const float* zr = zb + l * 64;   // wave-uniform -> s_load_dwordx16
#pragma unroll
        for (int q = 0; q < 16; q++) acc[q] += w * zr[q];
    }

    float4* Pv = (float4*)&P[(size_t)(m0 + m) * 64 + bg * 16];
#pragma unroll
    for (int q4 = 0; q4 < 4; q4++)
        Pv[q4] = make_float4(acc[q4 * 4 + 0], acc[q4 * 4 + 1],
                             acc[q4 * 4 + 2], acc[q4 * 4 + 3]);
}

// ---------------------------------------------------------------------------
// K9: out[b,j] = (sum_{m in elist(j)} P[m,b]) / max(ecnt[j],1).
// Branch-free 8-deep structure with rotate-prefetch of packed elist entries
// (round-8-proven; the asm-16 variant regressed here). lane = b; 32-j tile
// through LDS for coalesced out writes.
__global__ __launch_bounds__(256) void k_decode(const float* __restrict__ P,
        const int* __restrict__ ecnt, const int* __restrict__ offs,
        const int* __restrict__ elist, float* __restrict__ out) {
    __shared__ float tile[32][65];
    int t = threadIdx.x;
    int wv = __builtin_amdgcn_readfirstlane(t >> 6);
    int lane = t & 63;
    int j0 = blockIdx.x * 32;
    int jb = j0 + wv * 8;
    int c[8], o[8], cl[8];
    float acc[8];
#pragma unroll
    for (int s = 0; s < 8; s++) {
        int j = jb + s;
        bool v = (j < N_);
        c[s] = v ? __builtin_amdgcn_readfirstlane(ecnt[j]) : 0;
        o[s] = v ? __builtin_amdgcn_readfirstlane(offs[j]) : 0;
        cl[s] = max(c[s] - 1, 0);
        acc[s] = 0.f;
    }
    int cmax = 0;
#pragma unroll
    for (int s = 0; s < 8; s++) cmax = max(cmax, c[s]);

    if (cmax > 0) {
        int e[8];
#pragma unroll
        for (int s = 0; s < 8; s++)
            e[s] = __builtin_amdgcn_readfirstlane(elist[o[s]]);
        for (int q = 0; q < cmax; q++) {
            int en[8];
#pragma unroll
            for (int s = 0; s < 8; s++) {
                int p = o[s] + min(q + 1, cl[s]);
                en[s] = __builtin_amdgcn_readfirstlane(elist[p]);
            }
            int mm[8]; float sc[8];
#pragma unroll
            for (int s = 0; s < 8; s++) {
                bool valid = (q < c[s]);
                mm[s] = valid ? (e[s] & EMASK) : 0;
                sc[s] = valid ? 1.0f : 0.0f;
            }
            float row[8];
#pragma unroll
            for (int s = 0; s < 8; s++)
                row[s] = P[(size_t)mm[s] * 64 + lane];     // 8 gathers in flight
#pragma unroll
            for (int s = 0; s < 8; s++)
                acc[s] += row[s] * sc[s];
#pragma unroll
            for (int s = 0; s < 8; s++) e[s] = en[s];
        }
    }
#pragma unroll
    for (int s = 0; s < 8; s++) {
        int cc = (c[s] > 1) ? c[s] : 1;
        tile[wv * 8 + s][lane] = acc[s] * (1.0f / (float)cc);
    }
    __syncthreads();
#pragma unroll
    for (int r = 0; r < 8; r++) {
        int b = r * 8 + (t >> 5);
        int j = j0 + (t & 31);
        if (j < N_) out[(size_t)b * N_ + j] = tile[t & 31][b];
    }
}

// ---------------------------------------------------------------------------
extern "C" void kernel_launch(void* const* d_in, const int* in_sizes, int n_in,
                              void* d_out, int out_size, void* d_ws, size_t ws_size,
                              hipStream_t stream) {
    const float* We_m = (const float*)d_in[0];
    const float* be_m = (const float*)d_in[1];
    const float* Wd_m = (const float*)d_in[2];
    const float* bd_m = (const float*)d_in[3];
    const float* x    = (const float*)d_in[4];
    const int*   nn_n = (const int*)d_in[5];
    const int*   nn_m = (const int*)d_in[6];
    float* out = (float*)d_out;
    char* ws = (char*)d_ws;

    // Workspace layout (byte offsets). Region 0 holds P [S,64] (51.2 MB)
    // for the decode phase.
    float* P     = (float*)(ws + 0);
    int*   c_m   = (int*)(ws + 64012288);      //    800,000 B (zeroed)
    int*   ecnt  = (int*)(ws + 64812288);      //  1,000,000 B (zeroed)
    int*   fill  = (int*)(ws + 65812288);      //  1,000,000 B (zeroed)
    int*   added = (int*)(ws + 66812288);      //  1,000,000 B
    int*   offs  = (int*)(ws + 67812288);      //  1,000,000 B
    int*   elist = (int*)(ws + 68812288);      //  2,000,000 B (<= (S+N)*4 = 1.8 MB)
    float* zp2   = (float*)(ws + 70812288);    //  1,048,576 B (64 x 4096, zeroed)
    float* z2g   = (float*)(ws + 71860864);    //     16,384 B
    int*   bsum  = (int*)(ws + 71877248);      //      1,024 B
    // total ~71.9 MB

    hipMemsetAsync(ws + 64012288, 0, 2800000, stream);       // c_m, ecnt, fill
    hipMemsetAsync(zp2, 0, 1048576, stream);                 // zp2

    k_added_counts<<<977, 256, 0, stream>>>(nn_n, nn_m, added, c_m, ecnt);
    k_scan_blocksum<<<245, 256, 0, stream>>>(ecnt, bsum);
    k_scan_apply<<<245, 256, 0, stream>>>(ecnt, bsum, offs);
    k_fill<<<977, 256, 0, stream>>>(nn_m, nn_n, added, offs, c_m, fill, elist);
    k_wenc<<<FUSE_BLOCKS, 256, 0, stream>>>(x, We_m, ecnt, offs, elist, zp2);
    k_zred<<<16, 256, 0, stream>>>(zp2, be_m, z2g);
    k_pmat<<<3125, 256, 0, stream>>>(Wd_m, bd_m, z2g, P);
    k_decode<<<DEC_BLOCKS, 256, 0, stream>>>(P, ecnt, offs, elist, out);
}

// Round 14
// 321.187 us; speedup vs baseline: 1.0599x; 1.0486x over previous
//
#include <hip/hip_runtime.h>

// Problem constants (match reference)
constexpr int S_ = 200000;   // master nodes
constexpr int N_ = 250000;   // new nodes
// L = B = 64

constexpr int NCHUNK = (N_ + 63) / 64;        // 3907
constexpr int DEC_BLOCKS = (N_ + 31) / 32;    // 7813

constexpr int EMASK = 0x3FFFF;                // low 18 bits: master index

typedef __attribute__((ext_vector_type(8))) short bf16x8;
typedef __attribute__((ext_vector_type(4))) float f32x4;
typedef __attribute__((ext_vector_type(8))) unsigned short us8;

// ---------------------------------------------------------------------------
// K1: added[n] = (nn_m[nn_n[n]] != n); c_m histogram (added only, over nn_n);
//     ecnt[j] = #masters with nn_m=j  +  added[j]  (extended segment size).
__global__ void k_added_counts(const int* __restrict__ nn_n, const int* __restrict__ nn_m,
                               int* __restrict__ added, int* __restrict__ c_m,
                               int* __restrict__ ecnt) {
    int i = blockIdx.x * 256 + threadIdx.x;
    if (i < N_) {
        int m = nn_n[i];
        int a = (nn_m[m] != i) ? 1 : 0;
        added[i] = a;
        if (a) {
            atomicAdd(&c_m[m], 1);
            atomicAdd(&ecnt[i], 1);
        }
    }
    if (i < S_) {
        atomicAdd(&ecnt[nn_m[i]], 1);
    }
}

// ---------------------------------------------------------------------------
// K2: per-block sums of ecnt (1024 elements / block) for the exclusive scan.
__global__ void k_scan_blocksum(const int* __restrict__ ecnt, int* __restrict__ bsum) {
    __shared__ int sd[256];
    int b = blockIdx.x, t = threadIdx.x;
    int base = b * 1024 + t * 4;
    int s = 0;
#pragma unroll
    for (int k = 0; k < 4; k++) { int idx = base + k; if (idx < N_) s += ecnt[idx]; }
    sd[t] = s;
    __syncthreads();
    for (int off = 128; off > 0; off >>= 1) {
        if (t < off) sd[t] += sd[t + off];
        __syncthreads();
    }
    if (t == 0) bsum[b] = sd[0];
}

// K3: exclusive scan -> offs.
__global__ void k_scan_apply(const int* __restrict__ ecnt, const int* __restrict__ bsum,
                             int* __restrict__ offs) {
    __shared__ int sd[256];
    __shared__ int sp[256];
    int b = blockIdx.x, t = threadIdx.x;
    sp[t] = (t < b) ? bsum[t] : 0;
    __syncthreads();
    for (int off = 128; off > 0; off >>= 1) {
        if (t < off) sp[t] += sp[t + off];
        __syncthreads();
    }
    int prev = sp[0];

    int base = b * 1024 + t * 4;
    int v[4]; int s = 0;
#pragma unroll
    for (int k = 0; k < 4; k++) { int idx = base + k; v[k] = (idx < N_) ? ecnt[idx] : 0; s += v[k]; }
    sd[t] = s;
    __syncthreads();
    for (int off = 1; off < 256; off <<= 1) {
        int xv = (t >= off) ? sd[t - off] : 0;
        __syncthreads();
        sd[t] += xv;
        __syncthreads();
    }
    int run = prev + sd[t] - s;
#pragma unroll
    for (int k = 0; k < 4; k++) {
        int idx = base + k;
        if (idx < N_) offs[idx] = run;
        run += v[k];
    }
}

// K4: extended CSR fill — masters (nn_m inverse) plus the added contributor
//     nn_n[j] appended to segment j. Entries PACKED: m | (c_m[m] << 18)
//     (m < 2^18; c_m max ~15) so gather loops need no dependent c_m load.
__global__ void k_fill(const int* __restrict__ nn_m, const int* __restrict__ nn_n,
                       const int* __restrict__ added, const int* __restrict__ offs,
                       const int* __restrict__ c_m,
                       int* __restrict__ fill, int* __restrict__ elist) {
    int i = blockIdx.x * 256 + threadIdx.x;
    if (i < S_) {
        int j = nn_m[i];
        int p = atomicAdd(&fill[j], 1);
        elist[offs[j] + p] = i | (c_m[i] << 18);        // coalesced c_m read
    }
    if (i < N_ && added[i]) {
        int m = nn_n[i];
        int p = atomicAdd(&fill[i], 1);
        elist[offs[i] + p] = m | (c_m[m] << 18);        // random, L2-resident
    }
}

// ---------------------------------------------------------------------------
// K5 (FUSED k_wen + k_encode): ONE chunk of 64 j's per block (v15: was 2 —
// grid 3907 oversubscribes ~15 blocks/CU vs ~8 resident, so the scheduler
// backfills straggler tails; v14's all-resident grid ran at 38% time-avg
// occupancy from cmax-variance stragglers with no queued blocks).
//   phase G: We_n[j,:] = sum_{m in elist(j)} We_m[m,:] * rcp(c_m+1).
//     16 segments per wave; branch-free clamp, packed elist; 16 asm-forced
//     row gathers per round + one s_waitcnt vmcnt(0) + sched_barrier(0)
//     (v10-proven; v12's counted-vmcnt pipeline raced and is not retried).
//     hi/lo bf16 split written to the 16 KB LDS fragment image
//     sw[sH*4096 + ct*1024 + hl*512 + (l15+16*kq2)*8 + i],
//     sH=wv>>1, kq2=(wv&1)*2+(u>>3), i=u&7  (each slot written once).
//   phase M: encode MFMA z[b,l] += x[b,n]*We_n[n,l], fp32 emulated by
//     bf16 hi/lo (ah*bh + al*bh + ah*bl); B via ds_read_b128 from sw.
// Epilogue: dense atomicAdd into zp2[row][b*64+l], row = blockIdx & 63.
__global__ __launch_bounds__(256) void k_wenc(
        const float* __restrict__ x, const float* __restrict__ We_m,
        const int* __restrict__ ecnt, const int* __restrict__ offs,
        const int* __restrict__ elist, float* __restrict__ zp2) {
    __shared__ unsigned short sw[8192];   // 16 KB fragment image (one chunk)
    int t = threadIdx.x;
    int lane = t & 63;
    int wv = __builtin_amdgcn_readfirstlane(t >> 6);
    int mrow = lane & 15;                 // A row within band / C col
    int kq = lane >> 4;                   // A k-quad / C row-quad
    int ct = lane >> 4, l15 = lane & 15;  // gather-epilogue coords
    const float* xbase = x + (size_t)(wv * 16 + mrow) * N_ + kq * 8;
    f32x4 acc[4];
#pragma unroll
    for (int i = 0; i < 4; i++) acc[i] = (f32x4){0.f, 0.f, 0.f, 0.f};

    int n0 = blockIdx.x * 64;             // one chunk per block

    // ---------------- phase G: 16 segments per wave ----------------
    int jb = n0 + wv * 16;
    int c[16], o[16];
    float ag[16];
#pragma unroll
    for (int u = 0; u < 16; u++) {
        int j = jb + u;
        bool v = (j < N_);
        c[u] = v ? __builtin_amdgcn_readfirstlane(ecnt[j]) : 0;
        o[u] = v ? __builtin_amdgcn_readfirstlane(offs[j]) : 0;
        ag[u] = 0.f;
    }
    int cmax = 0;
#pragma unroll
    for (int u = 0; u < 16; u++) cmax = max(cmax, c[u]);
    if (cmax > 0) {
        int e[16];
#pragma unroll
        for (int u = 0; u < 16; u++)
            e[u] = __builtin_amdgcn_readfirstlane(elist[o[u]]);
        for (int q = 0; q < cmax; q++) {
            float row[16];
#pragma unroll
            for (int u = 0; u < 16; u++) {              // gathers issue first
                int mmu = (q < c[u]) ? (e[u] & EMASK) : 0;
                const float* ap = We_m + (size_t)mmu * 64 + lane;
                asm volatile("global_load_dword %0, %1, off"
                             : "=v"(row[u]) : "v"(ap));
            }
            int en[16];
#pragma unroll
            for (int u = 0; u < 16; u++) {              // entry loads overlap
                int cl = max(c[u] - 1, 0);
                int p = o[u] + min(q + 1, cl);
                en[u] = __builtin_amdgcn_readfirstlane(elist[p]);
            }
            asm volatile("s_waitcnt vmcnt(0)");         // one drain per round
            __builtin_amdgcn_sched_barrier(0);          // rule #18 fence
#pragma unroll
            for (int u = 0; u < 16; u++) {
                float r = __builtin_amdgcn_rcpf((float)((e[u] >> 18) + 1));
                float sc = (q < c[u]) ? r : 0.0f;
                ag[u] += row[u] * sc;
            }
#pragma unroll
            for (int u = 0; u < 16; u++) e[u] = en[u];
        }
    }
    // group epilogue: hi/lo split -> two contiguous us8 runs each
    us8 h0, l0, h1, l1;
#pragma unroll
    for (int s = 0; s < 8; s++) {
        float v0 = ag[s];
        unsigned u0 = __float_as_uint(v0);
        h0[s] = (unsigned short)(u0 >> 16);
        float r0 = v0 - __uint_as_float(u0 & 0xffff0000u);
        l0[s] = (unsigned short)(__float_as_uint(r0) >> 16);
        float v1 = ag[8 + s];
        unsigned u1 = __float_as_uint(v1);
        h1[s] = (unsigned short)(u1 >> 16);
        float r1 = v1 - __uint_as_float(u1 & 0xffff0000u);
        l1[s] = (unsigned short)(__float_as_uint(r1) >> 16);
    }
    int kq2a = (wv & 1) * 2;
    int sH = wv >> 1;
    int base0 = sH * 4096 + ct * 1024 + (l15 + 16 * kq2a) * 8;
    int base1 = base0 + 128;          // kq2a+1
    *(us8*)&sw[base0]       = h0;
    *(us8*)&sw[base0 + 512] = l0;
    *(us8*)&sw[base1]       = h1;
    *(us8*)&sw[base1 + 512] = l1;
    __syncthreads();                  // fragment image complete

    // ---------------- phase M: MFMA over the chunk ----------------
#pragma unroll
    for (int s = 0; s < 2; s++) {
        // A raw load (8 consecutive fp32 along k), tail-guarded
        float av[8];
        if (n0 + s * 32 + kq * 8 + 8 <= N_) {
            float4 a0 = *(const float4*)(xbase + n0 + s * 32);
            float4 a1 = *(const float4*)(xbase + n0 + s * 32 + 4);
            av[0] = a0.x; av[1] = a0.y; av[2] = a0.z; av[3] = a0.w;
            av[4] = a1.x; av[5] = a1.y; av[6] = a1.z; av[7] = a1.w;
        } else {
#pragma unroll
            for (int i = 0; i < 8; i++) av[i] = 0.f;
        }
        // B fragments from LDS (contiguous b128, conflict-free)
        bf16x8 bh[4], bl[4];
#pragma unroll
        for (int c2 = 0; c2 < 4; c2++) {
            bh[c2] = *(const bf16x8*)&sw[s * 4096 + c2 * 1024 + lane * 8];
            bl[c2] = *(const bf16x8*)&sw[s * 4096 + c2 * 1024 + 512 + lane * 8];
        }
        // split A into hi/lo bf16
        bf16x8 ah, al;
#pragma unroll
        for (int i = 0; i < 8; i++) {
            float v = av[i];
            unsigned u = __float_as_uint(v);
            ah[i] = (short)(u >> 16);
            float r = v - __uint_as_float(u & 0xffff0000u);
            al[i] = (short)(__float_as_uint(r) >> 16);
        }
        // 12 MFMAs: 4 col-tiles x 3 split terms
#pragma unroll
        for (int c2 = 0; c2 < 4; c2++) {
            acc[c2] = __builtin_amdgcn_mfma_f32_16x16x32_bf16(ah, bh[c2], acc[c2], 0, 0, 0);
            acc[c2] = __builtin_amdgcn_mfma_f32_16x16x32_bf16(al, bh[c2], acc[c2], 0, 0, 0);
            acc[c2] = __builtin_amdgcn_mfma_f32_16x16x32_bf16(ah, bl[c2], acc[c2], 0, 0, 0);
        }
    }

    // Epilogue: C/D layout col=lane&15, row=(lane>>4)*4+reg (verified m89).
    int row = blockIdx.x & 63;
    float* zr = zp2 + row * 4096;
#pragma unroll
    for (int c2 = 0; c2 < 4; c2++) {
#pragma unroll
        for (int r = 0; r < 4; r++) {
            int b = wv * 16 + kq * 4 + r;
            int l = c2 * 16 + mrow;
            atomicAdd(&zr[b * 64 + l], acc[c2][r]);   // 16 consecutive floats/quad
        }
    }
}

// K7: z2g[l*64+b] = sum_rows zp2[b*64+l] + be[l].  (zp2 is b-major)
__global__ void k_zred(const float* __restrict__ zp2, const float* __restrict__ be_m,
                       float* __restrict__ z2g) {
    int slot = blockIdx.x * 256 + threadIdx.x;   // 16 blocks x 256, slot = b*64+l
    float s = 0.f;
    for (int r = 0; r < 64; r++) s += zp2[r * 4096 + slot];
    int b = slot >> 6, l = slot & 63;
    z2g[l * 64 + b] = s + be_m[l];
}

// ---------------------------------------------------------------------------
// K8: P16[m,b] = bf16(sum_l z2g[l*64+b] * Wd_m[l,m] + bd_m[m]).  [S][64] bf16.
// acc[16] per thread (lane = m, wave bg owns b-group). v15: P stored as
// RNE-rounded bf16 — halves k_decode's random-gather bytes (115 -> 57.6 MB)
// and pmat's write volume. Precision: |P|<~8, bf16 err ~0.006-0.03, out sums
// ~1.8 rows -> absmax ~0.05 vs 0.13 threshold.
__global__ __launch_bounds__(256) void k_pmat(
        const float* __restrict__ Wd_m, const float* __restrict__ bd_m,
        const float* __restrict__ z2g, unsigned short* __restrict__ P16) {
    __shared__ float ws[64 * 64];
    int t = threadIdx.x;
    int m0 = blockIdx.x * 64;
    // stage Wd_m[l][m0:m0+64] tile: 4 float4 loads per thread, coalesced
#pragma unroll
    for (int r = 0; r < 4; r++) {
        int flat = r * 256 + t;          // 0..1023
        int l = flat >> 4;               // 0..63
        int c4 = flat & 15;              // 0..15
        float4 v = *(const float4*)&Wd_m[(size_t)l * S_ + m0 + c4 * 4];
        *(float4*)&ws[l * 64 + c4 * 4] = v;
    }
    __syncthreads();

    int m = t & 63;
    int bg = __builtin_amdgcn_readfirstlane(t >> 6);   // wave-uniform b-group
    float bd = bd_m[m0 + m];
    float acc[16];
#pragma unroll
    for (int q = 0; q < 16; q++) acc[q] = bd;
    const float* zb = z2g + bg * 16;
#pragma unroll 4
    for (int l = 0; l < 64; l++) {
        float w = ws[l * 64 + m];
        const float* zr = zb + l * 64;   // wave-uniform -> s_load_dwordx16
#pragma unroll
        for (int q = 0; q < 16; q++) acc[q] += w * zr[q];
    }

    us8 hv[2];
#pragma unroll
    for (int q = 0; q < 16; q++) {
        unsigned u = __float_as_uint(acc[q]);
        u += 0x7fffu + ((u >> 16) & 1);                // RNE to bf16
        hv[q >> 3][q & 7] = (unsigned short)(u >> 16);
    }
    unsigned short* pp = P16 + (size_t)(m0 + m) * 64 + bg * 16;
    *(us8*)pp       = hv[0];
    *(us8*)(pp + 8) = hv[1];
}

// ---------------------------------------------------------------------------
// K9: out[b,j] = (sum_{m in elist(j)} P16[m,b]) / max(ecnt[j],1).
// Branch-free 8-deep structure with rotate-prefetch of packed elist entries
// (round-8-proven). P rows are bf16 (2B/lane, 128B/row — half the gather
// bytes/lines of f32). lane = b; 32-j tile through LDS for coalesced writes.
__global__ __launch_bounds__(256) void k_decode(const unsigned short* __restrict__ P16,
        const int* __restrict__ ecnt, const int* __restrict__ offs,
        const int* __restrict__ elist, float* __restrict__ out) {
    __shared__ float tile[32][65];
    int t = threadIdx.x;
    int wv = __builtin_amdgcn_readfirstlane(t >> 6);
    int lane = t & 63;
    int j0 = blockIdx.x * 32;
    int jb = j0 + wv * 8;
    int c[8], o[8], cl[8];
    float acc[8];
#pragma unroll
    for (int s = 0; s < 8; s++) {
        int j = jb + s;
        bool v = (j < N_);
        c[s] = v ? __builtin_amdgcn_readfirstlane(ecnt[j]) : 0;
        o[s] = v ? __builtin_amdgcn_readfirstlane(offs[j]) : 0;
        cl[s] = max(c[s] - 1, 0);
        acc[s] = 0.f;
    }
    int cmax = 0;
#pragma unroll
    for (int s = 0; s < 8; s++) cmax = max(cmax, c[s]);

    if (cmax > 0) {
        int e[8];
#pragma unroll
        for (int s = 0; s < 8; s++)
            e[s] = __builtin_amdgcn_readfirstlane(elist[o[s]]);
        for (int q = 0; q < cmax; q++) {
            int en[8];
#pragma unroll
            for (int s = 0; s < 8; s++) {
                int p = o[s] + min(q + 1, cl[s]);
                en[s] = __builtin_amdgcn_readfirstlane(elist[p]);
            }
            int mm[8]; float sc[8];
#pragma unroll
            for (int s = 0; s < 8; s++) {
                bool valid = (q < c[s]);
                mm[s] = valid ? (e[s] & EMASK) : 0;
                sc[s] = valid ? 1.0f : 0.0f;
            }
            float row[8];
#pragma unroll
            for (int s = 0; s < 8; s++) {
                unsigned short rw = P16[(size_t)mm[s] * 64 + lane];  // 8 in flight
                row[s] = __uint_as_float((unsigned)rw << 16);
            }
#pragma unroll
            for (int s = 0; s < 8; s++)
                acc[s] += row[s] * sc[s];
#pragma unroll
            for (int s = 0; s < 8; s++) e[s] = en[s];
        }
    }
#pragma unroll
    for (int s = 0; s < 8; s++) {
        int cc = (c[s] > 1) ? c[s] : 1;
        tile[wv * 8 + s][lane] = acc[s] * (1.0f / (float)cc);
    }
    __syncthreads();
#pragma unroll
    for (int r = 0; r < 8; r++) {
        int b = r * 8 + (t >> 5);
        int j = j0 + (t & 31);
        if (j < N_) out[(size_t)b * N_ + j] = tile[t & 31][b];
    }
}

// ---------------------------------------------------------------------------
extern "C" void kernel_launch(void* const* d_in, const int* in_sizes, int n_in,
                              void* d_out, int out_size, void* d_ws, size_t ws_size,
                              hipStream_t stream) {
    const float* We_m = (const float*)d_in[0];
    const float* be_m = (const float*)d_in[1];
    const float* Wd_m = (const float*)d_in[2];
    const float* bd_m = (const float*)d_in[3];
    const float* x    = (const float*)d_in[4];
    const int*   nn_n = (const int*)d_in[5];
    const int*   nn_m = (const int*)d_in[6];
    float* out = (float*)d_out;
    char* ws = (char*)d_ws;

    // Workspace layout (byte offsets). Region 0 holds P16 [S,64] bf16
    // (25.6 MB) for the decode phase.
    unsigned short* P16 = (unsigned short*)(ws + 0);
    int*   c_m   = (int*)(ws + 64012288);      //    800,000 B (zeroed)
    int*   ecnt  = (int*)(ws + 64812288);      //  1,000,000 B (zeroed)
    int*   fill  = (int*)(ws + 65812288);      //  1,000,000 B (zeroed)
    int*   added = (int*)(ws + 66812288);      //  1,000,000 B
    int*   offs  = (int*)(ws + 67812288);      //  1,000,000 B
    int*   elist = (int*)(ws + 68812288);      //  2,000,000 B (<= (S+N)*4 = 1.8 MB)
    float* zp2   = (float*)(ws + 70812288);    //  1,048,576 B (64 x 4096, zeroed)
    float* z2g   = (float*)(ws + 71860864);    //     16,384 B
    int*   bsum  = (int*)(ws + 71877248);      //      1,024 B
    // total ~71.9 MB

    hipMemsetAsync(ws + 64012288, 0, 2800000, stream);       // c_m, ecnt, fill
    hipMemsetAsync(zp2, 0, 1048576, stream);                 // zp2

    k_added_counts<<<977, 256, 0, stream>>>(nn_n, nn_m, added, c_m, ecnt);
    k_scan_blocksum<<<245, 256, 0, stream>>>(ecnt, bsum);
    k_scan_apply<<<245, 256, 0, stream>>>(ecnt, bsum, offs);
    k_fill<<<977, 256, 0, stream>>>(nn_m, nn_n, added, offs, c_m, fill, elist);
    k_wenc<<<NCHUNK, 256, 0, stream>>>(x, We_m, ecnt, offs, elist, zp2);
    k_zred<<<16, 256, 0, stream>>>(zp2, be_m, z2g);
    k_pmat<<<3125, 256, 0, stream>>>(Wd_m, bd_m, z2g, P16);
    k_decode<<<DEC_BLOCKS, 256, 0, stream>>>(P16, ecnt, offs, elist, out);
}